// Round 1
// baseline (5500.565 us; speedup 1.0000x reference)
//
#include <hip/hip_runtime.h>
#include <hip/hip_bf16.h>
#include <math.h>

#define H 128
#define TM 32

// h[n,f] = f<64 ? x[n,f] : 0
__global__ __launch_bounds__(256) void k_init_h(const float* __restrict__ x,
                                                float* __restrict__ h, int N) {
  int i = blockIdx.x * 256 + threadIdx.x;
  if (i < N * H) {
    int f = i & (H - 1);
    int n = i >> 7;
    h[i] = (f < 64) ? x[n * 64 + f] : 0.f;
  }
}

// WT[l][j][k] = W[l][k][j]  (so all matmuls are A @ B^T with B rows = out cols)
__global__ __launch_bounds__(256) void k_transposeW(const float* __restrict__ W,
                                                    float* __restrict__ WT) {
  int idx = blockIdx.x * 256 + threadIdx.x;
  if (idx < 3 * H * H) {
    int l = idx >> 14;
    int r = idx & (H * H - 1);
    int j = r >> 7;
    int k = r & (H - 1);
    WT[idx] = W[l * H * H + k * H + j];
  }
}

// C[n,j] = epi( sum_k A[n,k] * Wt[j,k] + bias[j] )
// epi 0: identity
// epi 1: sigmoid(v + X1[n,j])              (r and z gates)
// epi 2: tanh(X1[n,j] + X2[n,j] * v)       (n gate: X1=in_, X2=r, v=hn+b)
__global__ __launch_bounds__(256) void k_mm128(const float* __restrict__ A,
                                               const float* __restrict__ Wt,
                                               const float* __restrict__ bias,
                                               const float* __restrict__ X1,
                                               const float* __restrict__ X2,
                                               float* __restrict__ C, int N, int epi) {
  __shared__ float4 As4[TM * 32];  // TM rows x 128 floats
  int n0 = blockIdx.x * TM;
  int t = threadIdx.x;
  int nrows = N - n0; if (nrows > TM) nrows = TM;
  const float4* A4 = (const float4*)(A + (size_t)n0 * H);
#pragma unroll
  for (int i = 0; i < 4; i++) {
    int idx = t + i * 256;          // float4 index in [0, TM*32)
    int row = idx >> 5;
    if (row < nrows) As4[idx] = A4[idx];
  }
  __syncthreads();
  int j = t & (H - 1);              // output column
  int half = t >> 7;                // 0/1 -> which 16 rows
  int nbase = half * (TM / 2);
  float acc[TM / 2];
#pragma unroll
  for (int i = 0; i < TM / 2; i++) acc[i] = 0.f;
  const float4* w4 = (const float4*)(Wt + (size_t)j * H);
  for (int k4 = 0; k4 < 32; k4++) {
    float4 w = w4[k4];
#pragma unroll
    for (int i = 0; i < TM / 2; i++) {
      float4 a = As4[(nbase + i) * 32 + k4];   // LDS broadcast across wave
      acc[i] += a.x * w.x + a.y * w.y + a.z * w.z + a.w * w.w;
    }
  }
  float b = bias ? bias[j] : 0.f;
#pragma unroll
  for (int i = 0; i < TM / 2; i++) {
    int n = n0 + nbase + i;
    if (n < N) {
      size_t o = (size_t)n * H + j;
      float v = acc[i] + b;
      if (epi == 1)      v = 1.f / (1.f + expf(-(v + X1[o])));
      else if (epi == 2) v = tanhf(X1[o] + X2[o] * v);
      C[o] = v;
    }
  }
}

// agg[dst[e]] += m[src[e]] ; 32 threads per edge, float4 each
__global__ __launch_bounds__(256) void k_scatter(const float* __restrict__ m,
                                                 const int* __restrict__ src,
                                                 const int* __restrict__ dst,
                                                 float* __restrict__ agg, int E) {
  int tid = blockIdx.x * 256 + threadIdx.x;
  int e = tid >> 5;
  int lane = tid & 31;
  if (e >= E) return;
  int s = src[e];
  int d = dst[e];
  float4 v = ((const float4*)(m + (size_t)s * H))[lane];
  float* ad = agg + (size_t)d * H + lane * 4;
  atomicAdd(ad + 0, v.x);
  atomicAdd(ad + 1, v.y);
  atomicAdd(ad + 2, v.z);
  atomicAdd(ad + 3, v.w);
}

// h = (1-z)*n + z*h
__global__ __launch_bounds__(256) void k_gru_out(float* __restrict__ h,
                                                 const float* __restrict__ z,
                                                 const float* __restrict__ n, int total) {
  int i = blockIdx.x * 256 + threadIdx.x;
  if (i < total) {
    float zz = z[i];
    h[i] = (1.f - zz) * n[i] + zz * h[i];
  }
}

// out[n,:] = log_softmax(h[n,:] @ lin_w^T + lin_b); one wave per node
__global__ __launch_bounds__(256) void k_classify(const float* __restrict__ h,
                                                  const float* __restrict__ lw,
                                                  const float* __restrict__ lb,
                                                  float* __restrict__ out, int N) {
  int wave = (blockIdx.x * 256 + threadIdx.x) >> 6;
  int lane = threadIdx.x & 63;
  if (wave >= N) return;
  int c = lane & 15;    // class
  int q = lane >> 4;    // K-quarter
  const float* hr = h + (size_t)wave * H + q * 32;
  const float* wr = lw + c * H + q * 32;
  float p = 0.f;
#pragma unroll
  for (int k = 0; k < 32; k += 4) {
    float4 a = *(const float4*)(hr + k);
    float4 w = *(const float4*)(wr + k);
    p += a.x * w.x + a.y * w.y + a.z * w.z + a.w * w.w;
  }
  p += __shfl_xor(p, 16, 64);
  p += __shfl_xor(p, 32, 64);
  float z = p + lb[c];
  float mx = z;
#pragma unroll
  for (int d = 1; d < 16; d <<= 1) mx = fmaxf(mx, __shfl_xor(mx, d, 64));
  float e = expf(z - mx);
  float s = e;
#pragma unroll
  for (int d = 1; d < 16; d <<= 1) s += __shfl_xor(s, d, 64);
  if (q == 0) out[(size_t)wave * 16 + c] = z - mx - logf(s);
}

extern "C" void kernel_launch(void* const* d_in, const int* in_sizes, int n_in,
                              void* d_out, int out_size, void* d_ws, size_t ws_size,
                              hipStream_t stream) {
  const float* x   = (const float*)d_in[0];
  const int*   ei  = (const int*)d_in[1];
  const float* W   = (const float*)d_in[2];
  const float* wih = (const float*)d_in[3];
  const float* whh = (const float*)d_in[4];
  const float* bih = (const float*)d_in[5];
  const float* bhh = (const float*)d_in[6];
  const float* lw  = (const float*)d_in[7];
  const float* lb  = (const float*)d_in[8];
  float* out = (float*)d_out;

  int N = in_sizes[0] / 64;   // 50000
  int E = in_sizes[1] / 2;    // 800000
  const int* src = ei;        // edge_index[0]
  const int* dst = ei + E;    // edge_index[1]

  size_t NH = (size_t)N * H;
  float* B0 = (float*)d_ws;   // h        [N,128]
  float* B1 = B0 + NH;        // m / in_ / n
  float* B2 = B1 + NH;        // agg
  float* B3 = B2 + NH;        // ir / r / iz / z
  float* WT = B3 + NH;        // 3*128*128

  int nb_nh = (int)((NH + 255) / 256);
  int nb_mm = (N + TM - 1) / TM;
  int nb_sc = (int)(((size_t)E * 32 + 255) / 256);

  k_init_h<<<nb_nh, 256, 0, stream>>>(x, B0, N);
  k_transposeW<<<(3 * H * H + 255) / 256, 256, 0, stream>>>(W, WT);

  for (int l = 0; l < 3; l++) {
    // m = h @ W[l]
    k_mm128<<<nb_mm, 256, 0, stream>>>(B0, WT + (size_t)l * H * H, nullptr,
                                       nullptr, nullptr, B1, N, 0);
    // agg = segment_sum(m[src], dst)
    hipMemsetAsync(B2, 0, NH * sizeof(float), stream);
    k_scatter<<<nb_sc, 256, 0, stream>>>(B1, src, dst, B2, E);
    // ir = agg @ w_ih_r^T + b_ih_r
    k_mm128<<<nb_mm, 256, 0, stream>>>(B2, wih + 0 * H * H, bih + 0 * H,
                                       nullptr, nullptr, B3, N, 0);
    // r = sigmoid(ir + (h @ w_hh_r^T + b_hh_r))
    k_mm128<<<nb_mm, 256, 0, stream>>>(B0, whh + 0 * H * H, bhh + 0 * H,
                                       B3, nullptr, B3, N, 1);
    // in_ = agg @ w_ih_n^T + b_ih_n
    k_mm128<<<nb_mm, 256, 0, stream>>>(B2, wih + 2 * H * H, bih + 2 * H,
                                       nullptr, nullptr, B1, N, 0);
    // n = tanh(in_ + r * (h @ w_hh_n^T + b_hh_n))
    k_mm128<<<nb_mm, 256, 0, stream>>>(B0, whh + 2 * H * H, bhh + 2 * H,
                                       B1, B3, B1, N, 2);
    // iz = agg @ w_ih_z^T + b_ih_z
    k_mm128<<<nb_mm, 256, 0, stream>>>(B2, wih + 1 * H * H, bih + 1 * H,
                                       nullptr, nullptr, B3, N, 0);
    // z = sigmoid(iz + (h @ w_hh_z^T + b_hh_z))
    k_mm128<<<nb_mm, 256, 0, stream>>>(B0, whh + 1 * H * H, bhh + 1 * H,
                                       B3, nullptr, B3, N, 1);
    // h = (1-z)*n + z*h
    k_gru_out<<<nb_nh, 256, 0, stream>>>(B0, B3, B1, (int)NH);
  }

  k_classify<<<(N + 3) / 4, 256, 0, stream>>>(B0, lw, lb, out, N);
}

// Round 2
// 3888.312 us; speedup vs baseline: 1.4146x; 1.4146x over previous
//
#include <hip/hip_runtime.h>
#include <hip/hip_bf16.h>
#include <math.h>

#define H 128
#define TM 32   // rows per block in k_mm128
#define GT 16   // rows per block in k_gru

// h[n,f] = f<64 ? x[n,f] : 0
__global__ __launch_bounds__(256) void k_init_h(const float* __restrict__ x,
                                                float* __restrict__ h, int N) {
  int i = blockIdx.x * 256 + threadIdx.x;
  if (i < N * H) {
    int f = i & (H - 1);
    int n = i >> 7;
    h[i] = (f < 64) ? x[n * 64 + f] : 0.f;
  }
}

// WT[l][j][k] = W[l][k][j]
__global__ __launch_bounds__(256) void k_transposeW(const float* __restrict__ W,
                                                    float* __restrict__ WT) {
  int idx = blockIdx.x * 256 + threadIdx.x;
  if (idx < 3 * H * H) {
    int l = idx >> 14;
    int r = idx & (H * H - 1);
    int j = r >> 7;
    int k = r & (H - 1);
    WT[idx] = W[l * H * H + k * H + j];
  }
}

// ---------- CSR build ----------
__global__ __launch_bounds__(256) void k_count(const int* __restrict__ dst,
                                               int* __restrict__ deg, int E) {
  int e = blockIdx.x * 256 + threadIdx.x;
  if (e < E) atomicAdd(&deg[dst[e]], 1);
}

// single-block exclusive scan over deg[N] -> rowptr[N+1]; cursor = copy
__global__ __launch_bounds__(256) void k_scan(const int* __restrict__ deg,
                                              int* __restrict__ rowptr,
                                              int* __restrict__ cursor, int N) {
  __shared__ int warp_sums[4];
  __shared__ int carry_s;
  int t = threadIdx.x;
  int lane = t & 63, w = t >> 6;
  if (t == 0) carry_s = 0;
  __syncthreads();
  for (int base = 0; base < N; base += 256) {
    int i = base + t;
    int v = (i < N) ? deg[i] : 0;
    int s = v;
#pragma unroll
    for (int d = 1; d < 64; d <<= 1) {
      int u = __shfl_up(s, d, 64);
      if (lane >= d) s += u;
    }
    if (lane == 63) warp_sums[w] = s;
    __syncthreads();
    int woff = 0;
    if (w >= 1) woff += warp_sums[0];
    if (w >= 2) woff += warp_sums[1];
    if (w >= 3) woff += warp_sums[2];
    int excl = carry_s + woff + s - v;
    if (i < N) { rowptr[i] = excl; cursor[i] = excl; }
    __syncthreads();
    if (t == 255) carry_s = carry_s + woff + s;
    __syncthreads();
  }
  if (t == 0) rowptr[N] = carry_s;
}

__global__ __launch_bounds__(256) void k_fill(const int* __restrict__ src,
                                              const int* __restrict__ dst,
                                              int* __restrict__ cursor,
                                              int* __restrict__ csr_src, int E) {
  int e = blockIdx.x * 256 + threadIdx.x;
  if (e < E) {
    int pos = atomicAdd(&cursor[dst[e]], 1);
    csr_src[pos] = src[e];
  }
}

// agg[n,:] = sum over csr edges of m[src,:]; one 64-lane wave per node, float2/lane
__global__ __launch_bounds__(256) void k_gather(const float* __restrict__ m,
                                                const int* __restrict__ rowptr,
                                                const int* __restrict__ csr_src,
                                                float* __restrict__ agg, int N) {
  int node = (blockIdx.x * 256 + threadIdx.x) >> 6;
  int lane = threadIdx.x & 63;
  if (node >= N) return;
  int b = rowptr[node], e = rowptr[node + 1];
  float2 acc = make_float2(0.f, 0.f);
  for (int i = b; i < e; i++) {
    int s = csr_src[i];
    float2 v = *(const float2*)(m + (size_t)s * H + lane * 2);
    acc.x += v.x; acc.y += v.y;
  }
  *(float2*)(agg + (size_t)node * H + lane * 2) = acc;
}

// ---------- m = h @ W[l] (A @ Wt^T form) ----------
__global__ __launch_bounds__(256) void k_mm128(const float* __restrict__ A,
                                               const float* __restrict__ Wt,
                                               float* __restrict__ C, int N) {
  __shared__ float4 As4[TM * 32];
  int n0 = blockIdx.x * TM;
  int t = threadIdx.x;
  int nrows = N - n0; if (nrows > TM) nrows = TM;
  const float4* A4 = (const float4*)(A + (size_t)n0 * H);
#pragma unroll
  for (int i = 0; i < 4; i++) {
    int idx = t + i * 256;
    int row = idx >> 5;
    if (row < nrows) As4[idx] = A4[idx];
  }
  __syncthreads();
  int j = t & (H - 1);
  int half = t >> 7;
  int nbase = half * (TM / 2);
  float acc[TM / 2];
#pragma unroll
  for (int i = 0; i < TM / 2; i++) acc[i] = 0.f;
  const float4* w4 = (const float4*)(Wt + (size_t)j * H);
  for (int k4 = 0; k4 < 32; k4++) {
    float4 w = w4[k4];
#pragma unroll
    for (int i = 0; i < TM / 2; i++) {
      float4 a = As4[(nbase + i) * 32 + k4];
      acc[i] += a.x * w.x + a.y * w.y + a.z * w.z + a.w * w.w;
    }
  }
#pragma unroll
  for (int i = 0; i < TM / 2; i++) {
    int n = n0 + nbase + i;
    if (n < N) C[(size_t)n * H + j] = acc[i];
  }
}

// ---------- fused GRU: h' = GRUCell(agg, h) ----------
// 512 threads; j = t&127 (column), quarter = t>>7 handles 4 of GT=16 rows.
// Per (n,j): 6 dot products (agg vs w_ih rows, h vs w_hh rows) + elementwise epilogue.
__global__ __launch_bounds__(512) void k_gru(float* __restrict__ h,
                                             const float* __restrict__ agg,
                                             const float* __restrict__ wih,
                                             const float* __restrict__ whh,
                                             const float* __restrict__ bih,
                                             const float* __restrict__ bhh,
                                             int N) {
  __shared__ float4 Hs4[GT * 32];
  __shared__ float4 As4[GT * 32];
  int n0 = blockIdx.x * GT;
  int t = threadIdx.x;
  int nrows = N - n0; if (nrows > GT) nrows = GT;
  const float4* H4 = (const float4*)(h + (size_t)n0 * H);
  const float4* A4 = (const float4*)(agg + (size_t)n0 * H);
  {
    int row = t >> 5;
    if (row < nrows) { Hs4[t] = H4[t]; As4[t] = A4[t]; }
  }
  __syncthreads();
  int j = t & (H - 1);
  int quarter = t >> 7;
  int rbase = quarter * 4;

  float aIR[4], aIZ[4], aIN[4], aHR[4], aHZ[4], aHN[4];
#pragma unroll
  for (int i = 0; i < 4; i++) { aIR[i]=aIZ[i]=aIN[i]=aHR[i]=aHZ[i]=aHN[i]=0.f; }

  const float4* wir4 = (const float4*)(wih + (size_t)(0 * H + j) * H);
  const float4* wiz4 = (const float4*)(wih + (size_t)(1 * H + j) * H);
  const float4* win4 = (const float4*)(wih + (size_t)(2 * H + j) * H);
  const float4* whr4 = (const float4*)(whh + (size_t)(0 * H + j) * H);
  const float4* whz4 = (const float4*)(whh + (size_t)(1 * H + j) * H);
  const float4* whn4 = (const float4*)(whh + (size_t)(2 * H + j) * H);

  for (int k4 = 0; k4 < 32; k4++) {
    float4 wir = wir4[k4], wiz = wiz4[k4], win = win4[k4];
    float4 whr = whr4[k4], whz = whz4[k4], whn = whn4[k4];
#pragma unroll
    for (int i = 0; i < 4; i++) {
      float4 av = As4[(rbase + i) * 32 + k4];
      float4 hv = Hs4[(rbase + i) * 32 + k4];
      aIR[i] += av.x*wir.x + av.y*wir.y + av.z*wir.z + av.w*wir.w;
      aIZ[i] += av.x*wiz.x + av.y*wiz.y + av.z*wiz.z + av.w*wiz.w;
      aIN[i] += av.x*win.x + av.y*win.y + av.z*win.z + av.w*win.w;
      aHR[i] += hv.x*whr.x + hv.y*whr.y + hv.z*whr.z + hv.w*whr.w;
      aHZ[i] += hv.x*whz.x + hv.y*whz.y + hv.z*whz.z + hv.w*whz.w;
      aHN[i] += hv.x*whn.x + hv.y*whn.y + hv.z*whn.z + hv.w*whn.w;
    }
  }
  float bir = bih[0 * H + j], biz = bih[1 * H + j], bin = bih[2 * H + j];
  float bhr = bhh[0 * H + j], bhz = bhh[1 * H + j], bhn = bhh[2 * H + j];
  const float* Hs = (const float*)Hs4;
#pragma unroll
  for (int i = 0; i < 4; i++) {
    int n = n0 + rbase + i;
    if (n < N) {
      float r  = 1.f / (1.f + expf(-(aIR[i] + bir + aHR[i] + bhr)));
      float z  = 1.f / (1.f + expf(-(aIZ[i] + biz + aHZ[i] + bhz)));
      float nn = tanhf(aIN[i] + bin + r * (aHN[i] + bhn));
      float hold = Hs[(rbase + i) * H + j];
      h[(size_t)n * H + j] = (1.f - z) * nn + z * hold;
    }
  }
}

// out[n,:] = log_softmax(h[n,:] @ lin_w^T + lin_b); one wave per node
__global__ __launch_bounds__(256) void k_classify(const float* __restrict__ h,
                                                  const float* __restrict__ lw,
                                                  const float* __restrict__ lb,
                                                  float* __restrict__ out, int N) {
  int wave = (blockIdx.x * 256 + threadIdx.x) >> 6;
  int lane = threadIdx.x & 63;
  if (wave >= N) return;
  int c = lane & 15;
  int q = lane >> 4;
  const float* hr = h + (size_t)wave * H + q * 32;
  const float* wr = lw + c * H + q * 32;
  float p = 0.f;
#pragma unroll
  for (int k = 0; k < 32; k += 4) {
    float4 a = *(const float4*)(hr + k);
    float4 w = *(const float4*)(wr + k);
    p += a.x * w.x + a.y * w.y + a.z * w.z + a.w * w.w;
  }
  p += __shfl_xor(p, 16, 64);
  p += __shfl_xor(p, 32, 64);
  float z = p + lb[c];
  float mx = z;
#pragma unroll
  for (int d = 1; d < 16; d <<= 1) mx = fmaxf(mx, __shfl_xor(mx, d, 64));
  float e = expf(z - mx);
  float s = e;
#pragma unroll
  for (int d = 1; d < 16; d <<= 1) s += __shfl_xor(s, d, 64);
  if (q == 0) out[(size_t)wave * 16 + c] = z - mx - logf(s);
}

extern "C" void kernel_launch(void* const* d_in, const int* in_sizes, int n_in,
                              void* d_out, int out_size, void* d_ws, size_t ws_size,
                              hipStream_t stream) {
  const float* x   = (const float*)d_in[0];
  const int*   ei  = (const int*)d_in[1];
  const float* W   = (const float*)d_in[2];
  const float* wih = (const float*)d_in[3];
  const float* whh = (const float*)d_in[4];
  const float* bih = (const float*)d_in[5];
  const float* bhh = (const float*)d_in[6];
  const float* lw  = (const float*)d_in[7];
  const float* lb  = (const float*)d_in[8];
  float* out = (float*)d_out;

  int N = in_sizes[0] / 64;   // 50000
  int E = in_sizes[1] / 2;    // 800000
  const int* src = ei;
  const int* dst = ei + E;

  size_t NH = (size_t)N * H;
  float* B0 = (float*)d_ws;        // h    [N,128]
  float* B1 = B0 + NH;             // m    [N,128]
  float* B2 = B1 + NH;             // agg  [N,128]
  float* WT = B2 + NH;             // 3*128*128
  int* deg     = (int*)(WT + 3 * H * H);
  int* rowptr  = deg + N;          // N+1
  int* cursor  = rowptr + N + 1;   // N
  int* csr_src = cursor + N;       // E

  int nb_nh = (int)((NH + 255) / 256);
  int nb_mm = (N + TM - 1) / TM;
  int nb_e  = (E + 255) / 256;
  int nb_ga = (N * 64 + 255) / 256;
  int nb_gr = (N + GT - 1) / GT;

  k_init_h<<<nb_nh, 256, 0, stream>>>(x, B0, N);
  k_transposeW<<<(3 * H * H + 255) / 256, 256, 0, stream>>>(W, WT);

  // CSR build (once per launch)
  hipMemsetAsync(deg, 0, (size_t)N * sizeof(int), stream);
  k_count<<<nb_e, 256, 0, stream>>>(dst, deg, E);
  k_scan<<<1, 256, 0, stream>>>(deg, rowptr, cursor, N);
  k_fill<<<nb_e, 256, 0, stream>>>(src, dst, cursor, csr_src, E);

  for (int l = 0; l < 3; l++) {
    k_mm128<<<nb_mm, 256, 0, stream>>>(B0, WT + (size_t)l * H * H, B1, N);
    k_gather<<<nb_ga, 256, 0, stream>>>(B1, rowptr, csr_src, B2, N);
    k_gru<<<nb_gr, 512, 0, stream>>>(B0, B2, wih, whh, bih, bhh, N);
  }

  k_classify<<<(N + 3) / 4, 256, 0, stream>>>(B0, lw, lb, out, N);
}

// Round 3
// 875.657 us; speedup vs baseline: 6.2816x; 4.4405x over previous
//
#include <hip/hip_runtime.h>
#include <hip/hip_bf16.h>
#include <math.h>

#define H 128

typedef __bf16 bf16x8 __attribute__((ext_vector_type(8)));
typedef float f32x4 __attribute__((ext_vector_type(4)));
typedef __hip_bfloat16 bf16;

__device__ __forceinline__ bf16x8 ldb8(const bf16* p) {
  return *(const bf16x8*)(const void*)p;
}

// h[n,f] = f<64 ? x[n,f] : 0  (fp32 canonical + bf16 copy)
__global__ __launch_bounds__(256) void k_init_h(const float* __restrict__ x,
                                                float* __restrict__ hf,
                                                bf16* __restrict__ hb, int N) {
  int i = blockIdx.x * 256 + threadIdx.x;
  if (i < N * H) {
    int f = i & (H - 1);
    int n = i >> 7;
    float v = (f < 64) ? x[n * 64 + f] : 0.f;
    hf[i] = v;
    hb[i] = __float2bfloat16(v);
  }
}

// generic fp32 -> bf16
__global__ __launch_bounds__(256) void k_cvt(const float* __restrict__ in,
                                             bf16* __restrict__ out, int n) {
  int i = blockIdx.x * 256 + threadIdx.x;
  if (i < n) out[i] = __float2bfloat16(in[i]);
}

// WT[l][j][k] = bf16(W[l][k][j])
__global__ __launch_bounds__(256) void k_cvtW(const float* __restrict__ W,
                                              bf16* __restrict__ WT) {
  int idx = blockIdx.x * 256 + threadIdx.x;
  if (idx < 3 * H * H) {
    int l = idx >> 14;
    int r = idx & (H * H - 1);
    int j = r >> 7;
    int k = r & (H - 1);
    WT[idx] = __float2bfloat16(W[l * H * H + k * H + j]);
  }
}

// ---------- CSR build ----------
__global__ __launch_bounds__(256) void k_count(const int* __restrict__ dst,
                                               int* __restrict__ deg, int E) {
  int e = blockIdx.x * 256 + threadIdx.x;
  if (e < E) atomicAdd(&deg[dst[e]], 1);
}

__global__ __launch_bounds__(256) void k_scan(const int* __restrict__ deg,
                                              int* __restrict__ rowptr,
                                              int* __restrict__ cursor, int N) {
  __shared__ int warp_sums[4];
  __shared__ int carry_s;
  int t = threadIdx.x;
  int lane = t & 63, w = t >> 6;
  if (t == 0) carry_s = 0;
  __syncthreads();
  for (int base = 0; base < N; base += 256) {
    int i = base + t;
    int v = (i < N) ? deg[i] : 0;
    int s = v;
#pragma unroll
    for (int d = 1; d < 64; d <<= 1) {
      int u = __shfl_up(s, d, 64);
      if (lane >= d) s += u;
    }
    if (lane == 63) warp_sums[w] = s;
    __syncthreads();
    int woff = 0;
    if (w >= 1) woff += warp_sums[0];
    if (w >= 2) woff += warp_sums[1];
    if (w >= 3) woff += warp_sums[2];
    int excl = carry_s + woff + s - v;
    if (i < N) { rowptr[i] = excl; cursor[i] = excl; }
    __syncthreads();
    if (t == 255) carry_s = carry_s + woff + s;
    __syncthreads();
  }
  if (t == 0) rowptr[N] = carry_s;
}

__global__ __launch_bounds__(256) void k_fill(const int* __restrict__ src,
                                              const int* __restrict__ dst,
                                              int* __restrict__ cursor,
                                              int* __restrict__ csr_src, int E) {
  int e = blockIdx.x * 256 + threadIdx.x;
  if (e < E) {
    int pos = atomicAdd(&cursor[dst[e]], 1);
    csr_src[pos] = src[e];
  }
}

// ---------- m = h @ W[l], bf16 MFMA; wave = 16 rows x 64 cols ----------
__global__ __launch_bounds__(256) void k_mm_mfma(const bf16* __restrict__ hbin,
                                                 const bf16* __restrict__ WTl,
                                                 bf16* __restrict__ mb,
                                                 int N, int nwaves) {
  int wid = (blockIdx.x * 256 + threadIdx.x) >> 6;
  if (wid >= nwaves) return;
  int lane = threadIdx.x & 63;
  int r = lane & 15, quad = lane >> 4, laneK = quad * 8;
  int colh = wid & 1;
  int rowt = wid >> 1;
  int row0 = rowt * 16;
  int ra = row0 + r; if (ra > N - 1) ra = N - 1;

  f32x4 acc[4];
#pragma unroll
  for (int c = 0; c < 4; c++) acc[c] = (f32x4){0.f, 0.f, 0.f, 0.f};

  const bf16* wbase = WTl + (size_t)(colh * 64) * H;
#pragma unroll
  for (int kb = 0; kb < 4; kb++) {
    int ko = kb * 32 + laneK;
    bf16x8 a = ldb8(hbin + (size_t)ra * H + ko);
#pragma unroll
    for (int c = 0; c < 4; c++) {
      bf16x8 b = ldb8(wbase + (size_t)(c * 16 + r) * H + ko);
      acc[c] = __builtin_amdgcn_mfma_f32_16x16x32_bf16(a, b, acc[c], 0, 0, 0);
    }
  }
#pragma unroll
  for (int c = 0; c < 4; c++) {
#pragma unroll
    for (int i = 0; i < 4; i++) {
      int row = row0 + quad * 4 + i;
      if (row < N) {
        int col = colh * 64 + c * 16 + r;
        mb[(size_t)row * H + col] = __float2bfloat16(acc[c][i]);
      }
    }
  }
}

// agg[n,:] = sum m[src,:]; one wave per node, bf16x2 per lane, fp32 accum
__global__ __launch_bounds__(256) void k_gather(const bf16* __restrict__ m,
                                                const int* __restrict__ rowptr,
                                                const int* __restrict__ csr_src,
                                                bf16* __restrict__ agg, int N) {
  int node = (blockIdx.x * 256 + threadIdx.x) >> 6;
  int lane = threadIdx.x & 63;
  if (node >= N) return;
  int b = rowptr[node], e = rowptr[node + 1];
  float ax = 0.f, ay = 0.f;
  const __hip_bfloat162* m2 = (const __hip_bfloat162*)m;
  for (int i = b; i < e; i++) {
    int s = csr_src[i];
    __hip_bfloat162 v = m2[(size_t)s * 64 + lane];
    ax += __bfloat162float(v.x);
    ay += __bfloat162float(v.y);
  }
  __hip_bfloat162 o;
  o.x = __float2bfloat16(ax);
  o.y = __float2bfloat16(ay);
  ((__hip_bfloat162*)agg)[(size_t)node * 64 + lane] = o;
}

// ---------- fused GRU via MFMA ----------
// wave = 32 rows x 16 cols; 6 gate GEMMs (K=128) + elementwise epilogue.
// hf (fp32) updated in place (each (row,col) owned by exactly one wave);
// bf16 h ping-pongs hbin -> hbout.
__global__ __launch_bounds__(256) void k_gru(float* __restrict__ hf,
                                             const bf16* __restrict__ hbin,
                                             bf16* __restrict__ hbout,
                                             const bf16* __restrict__ aggb,
                                             const bf16* __restrict__ wihb,
                                             const bf16* __restrict__ whhb,
                                             const float* __restrict__ bih,
                                             const float* __restrict__ bhh,
                                             int N, int nwaves) {
  int wid = (blockIdx.x * 256 + threadIdx.x) >> 6;
  if (wid >= nwaves) return;
  int lane = threadIdx.x & 63;
  int r = lane & 15, quad = lane >> 4, laneK = quad * 8;
  int colb = wid & 7;
  int rowp = wid >> 3;
  int row0 = rowp * 32;
  if (row0 >= N) return;
  int col = colb * 16 + r;
  int ra = row0 + r;      if (ra > N - 1) ra = N - 1;
  int rb = row0 + 16 + r; if (rb > N - 1) rb = N - 1;

  f32x4 aIR[2], aIZ[2], aIN[2], aHR[2], aHZ[2], aHN[2];
#pragma unroll
  for (int t = 0; t < 2; t++) {
    aIR[t] = (f32x4){0.f,0.f,0.f,0.f}; aIZ[t] = aIR[t]; aIN[t] = aIR[t];
    aHR[t] = aIR[t]; aHZ[t] = aIR[t]; aHN[t] = aIR[t];
  }

  size_t wo0 = (size_t)(0 * H + col) * H;
  size_t wo1 = (size_t)(1 * H + col) * H;
  size_t wo2 = (size_t)(2 * H + col) * H;

#pragma unroll
  for (int kb = 0; kb < 4; kb++) {
    int ko = kb * 32 + laneK;
    bf16x8 a0 = ldb8(aggb + (size_t)ra * H + ko);
    bf16x8 a1 = ldb8(aggb + (size_t)rb * H + ko);
    bf16x8 h0 = ldb8(hbin + (size_t)ra * H + ko);
    bf16x8 h1 = ldb8(hbin + (size_t)rb * H + ko);
    bf16x8 wr = ldb8(wihb + wo0 + ko);
    aIR[0] = __builtin_amdgcn_mfma_f32_16x16x32_bf16(a0, wr, aIR[0], 0, 0, 0);
    aIR[1] = __builtin_amdgcn_mfma_f32_16x16x32_bf16(a1, wr, aIR[1], 0, 0, 0);
    bf16x8 wz = ldb8(wihb + wo1 + ko);
    aIZ[0] = __builtin_amdgcn_mfma_f32_16x16x32_bf16(a0, wz, aIZ[0], 0, 0, 0);
    aIZ[1] = __builtin_amdgcn_mfma_f32_16x16x32_bf16(a1, wz, aIZ[1], 0, 0, 0);
    bf16x8 wn = ldb8(wihb + wo2 + ko);
    aIN[0] = __builtin_amdgcn_mfma_f32_16x16x32_bf16(a0, wn, aIN[0], 0, 0, 0);
    aIN[1] = __builtin_amdgcn_mfma_f32_16x16x32_bf16(a1, wn, aIN[1], 0, 0, 0);
    bf16x8 ur = ldb8(whhb + wo0 + ko);
    aHR[0] = __builtin_amdgcn_mfma_f32_16x16x32_bf16(h0, ur, aHR[0], 0, 0, 0);
    aHR[1] = __builtin_amdgcn_mfma_f32_16x16x32_bf16(h1, ur, aHR[1], 0, 0, 0);
    bf16x8 uz = ldb8(whhb + wo1 + ko);
    aHZ[0] = __builtin_amdgcn_mfma_f32_16x16x32_bf16(h0, uz, aHZ[0], 0, 0, 0);
    aHZ[1] = __builtin_amdgcn_mfma_f32_16x16x32_bf16(h1, uz, aHZ[1], 0, 0, 0);
    bf16x8 un = ldb8(whhb + wo2 + ko);
    aHN[0] = __builtin_amdgcn_mfma_f32_16x16x32_bf16(h0, un, aHN[0], 0, 0, 0);
    aHN[1] = __builtin_amdgcn_mfma_f32_16x16x32_bf16(h1, un, aHN[1], 0, 0, 0);
  }

  float bir = bih[col], biz = bih[H + col], bin = bih[2 * H + col];
  float bhr = bhh[col], bhz = bhh[H + col], bhn = bhh[2 * H + col];
#pragma unroll
  for (int t = 0; t < 2; t++) {
#pragma unroll
    for (int i = 0; i < 4; i++) {
      int row = row0 + t * 16 + quad * 4 + i;
      if (row < N) {
        float rg = 1.f / (1.f + expf(-(aIR[t][i] + bir + aHR[t][i] + bhr)));
        float zg = 1.f / (1.f + expf(-(aIZ[t][i] + biz + aHZ[t][i] + bhz)));
        float ng = tanhf(aIN[t][i] + bin + rg * (aHN[t][i] + bhn));
        size_t o = (size_t)row * H + col;
        float hold = hf[o];
        float hp = (1.f - zg) * ng + zg * hold;
        hf[o] = hp;
        hbout[o] = __float2bfloat16(hp);
      }
    }
  }
}

// out[n,:] = log_softmax(h[n,:] @ lin_w^T + lin_b); one wave per node (fp32 h)
__global__ __launch_bounds__(256) void k_classify(const float* __restrict__ h,
                                                  const float* __restrict__ lw,
                                                  const float* __restrict__ lb,
                                                  float* __restrict__ out, int N) {
  int wave = (blockIdx.x * 256 + threadIdx.x) >> 6;
  int lane = threadIdx.x & 63;
  if (wave >= N) return;
  int c = lane & 15;
  int q = lane >> 4;
  const float* hr = h + (size_t)wave * H + q * 32;
  const float* wr = lw + c * H + q * 32;
  float p = 0.f;
#pragma unroll
  for (int k = 0; k < 32; k += 4) {
    float4 a = *(const float4*)(hr + k);
    float4 w = *(const float4*)(wr + k);
    p += a.x * w.x + a.y * w.y + a.z * w.z + a.w * w.w;
  }
  p += __shfl_xor(p, 16, 64);
  p += __shfl_xor(p, 32, 64);
  float z = p + lb[c];
  float mx = z;
#pragma unroll
  for (int d = 1; d < 16; d <<= 1) mx = fmaxf(mx, __shfl_xor(mx, d, 64));
  float e = expf(z - mx);
  float s = e;
#pragma unroll
  for (int d = 1; d < 16; d <<= 1) s += __shfl_xor(s, d, 64);
  if (q == 0) out[(size_t)wave * 16 + c] = z - mx - logf(s);
}

extern "C" void kernel_launch(void* const* d_in, const int* in_sizes, int n_in,
                              void* d_out, int out_size, void* d_ws, size_t ws_size,
                              hipStream_t stream) {
  const float* x   = (const float*)d_in[0];
  const int*   ei  = (const int*)d_in[1];
  const float* W   = (const float*)d_in[2];
  const float* wih = (const float*)d_in[3];
  const float* whh = (const float*)d_in[4];
  const float* bih = (const float*)d_in[5];
  const float* bhh = (const float*)d_in[6];
  const float* lw  = (const float*)d_in[7];
  const float* lb  = (const float*)d_in[8];
  float* out = (float*)d_out;

  int N = in_sizes[0] / 64;   // 50000
  int E = in_sizes[1] / 2;    // 800000
  const int* src = ei;
  const int* dst = ei + E;

  size_t NH = (size_t)N * H;
  // workspace carve-up (16B-aligned chunks)
  float* hf  = (float*)d_ws;                 // [N,H] fp32 canonical h
  bf16* hb0  = (bf16*)(hf + NH);             // [N,H] bf16 h ping
  bf16* hb1  = hb0 + NH;                     // [N,H] bf16 h pong
  bf16* mb   = hb1 + NH;                     // [N,H] bf16 m
  bf16* aggb = mb + NH;                      // [N,H] bf16 agg
  bf16* WTb  = aggb + NH;                    // [3,H,H] bf16 W transposed
  bf16* wihb = WTb + 3 * H * H;              // [3H,H]
  bf16* whhb = wihb + 3 * H * H;             // [3H,H]
  int* deg     = (int*)(whhb + 3 * H * H);
  int* rowptr  = deg + N;
  int* cursor  = rowptr + N + 1;
  int* csr_src = cursor + N;                 // E

  int nb_nh = (int)((NH + 255) / 256);
  int nb_e  = (E + 255) / 256;
  int nb_w  = (3 * H * H + 255) / 256;

  int rowtiles = (N + 15) / 16;              // 3125
  int nw_mm = rowtiles * 2;                  // 6250 waves
  int nb_mm = (nw_mm * 64 + 255) / 256;
  int rowpairs = (rowtiles + 1) / 2;         // 1563
  int nw_gru = rowpairs * 8;                 // 12504 waves
  int nb_gru = (nw_gru * 64 + 255) / 256;
  int nb_ga = (N * 64 + 255) / 256;

  k_init_h<<<nb_nh, 256, 0, stream>>>(x, hf, hb0, N);
  k_cvtW<<<nb_w, 256, 0, stream>>>(W, WTb);
  k_cvt<<<nb_w, 256, 0, stream>>>(wih, wihb, 3 * H * H);
  k_cvt<<<nb_w, 256, 0, stream>>>(whh, whhb, 3 * H * H);

  // CSR build
  hipMemsetAsync(deg, 0, (size_t)N * sizeof(int), stream);
  k_count<<<nb_e, 256, 0, stream>>>(dst, deg, E);
  k_scan<<<1, 256, 0, stream>>>(deg, rowptr, cursor, N);
  k_fill<<<nb_e, 256, 0, stream>>>(src, dst, cursor, csr_src, E);

  bf16* hbp[2] = {hb0, hb1};
  for (int l = 0; l < 3; l++) {
    bf16* hin  = hbp[l & 1];
    bf16* hout = hbp[(l + 1) & 1];
    k_mm_mfma<<<nb_mm, 256, 0, stream>>>(hin, WTb + (size_t)l * H * H, mb, N, nw_mm);
    k_gather<<<nb_ga, 256, 0, stream>>>(mb, rowptr, csr_src, aggb, N);
    k_gru<<<nb_gru, 256, 0, stream>>>(hf, hin, hout, aggb, wihb, whhb,
                                      bih, bhh, N, nw_gru);
  }

  k_classify<<<(N + 3) / 4, 256, 0, stream>>>(hf, lw, lb, out, N);
}

// Round 4
// 624.029 us; speedup vs baseline: 8.8146x; 1.4032x over previous
//
#include <hip/hip_runtime.h>
#include <hip/hip_bf16.h>
#include <math.h>

#define H 128

typedef __bf16 bf16x8 __attribute__((ext_vector_type(8)));
typedef float f32x4 __attribute__((ext_vector_type(4)));
typedef __hip_bfloat16 bf16;

__device__ __forceinline__ bf16x8 ldb8(const bf16* p) {
  return *(const bf16x8*)(const void*)p;
}

// h[n,f] = f<64 ? x[n,f] : 0  (fp32 canonical + bf16 copy)
__global__ __launch_bounds__(256) void k_init_h(const float* __restrict__ x,
                                                float* __restrict__ hf,
                                                bf16* __restrict__ hb, int N) {
  int i = blockIdx.x * 256 + threadIdx.x;
  if (i < N * H) {
    int f = i & (H - 1);
    int n = i >> 7;
    float v = (f < 64) ? x[n * 64 + f] : 0.f;
    hf[i] = v;
    hb[i] = __float2bfloat16(v);
  }
}

__global__ __launch_bounds__(256) void k_cvt(const float* __restrict__ in,
                                             bf16* __restrict__ out, int n) {
  int i = blockIdx.x * 256 + threadIdx.x;
  if (i < n) out[i] = __float2bfloat16(in[i]);
}

// WT[l][j][k] = bf16(W[l][k][j])
__global__ __launch_bounds__(256) void k_cvtW(const float* __restrict__ W,
                                              bf16* __restrict__ WT) {
  int idx = blockIdx.x * 256 + threadIdx.x;
  if (idx < 3 * H * H) {
    int l = idx >> 14;
    int r = idx & (H * H - 1);
    int j = r >> 7;
    int k = r & (H - 1);
    WT[idx] = __float2bfloat16(W[l * H * H + k * H + j]);
  }
}

// ---------- CSR build ----------
__global__ __launch_bounds__(256) void k_count(const int* __restrict__ dst,
                                               int* __restrict__ deg, int E) {
  int e = blockIdx.x * 256 + threadIdx.x;
  if (e < E) atomicAdd(&deg[dst[e]], 1);
}

// pass 1: per-block (256-elem) sums
__global__ __launch_bounds__(256) void k_bsum(const int* __restrict__ deg,
                                              int* __restrict__ bsums, int N) {
  __shared__ int ws[4];
  int t = threadIdx.x;
  int i = blockIdx.x * 256 + t;
  int v = (i < N) ? deg[i] : 0;
#pragma unroll
  for (int d = 1; d < 64; d <<= 1) v += __shfl_xor(v, d, 64);
  if ((t & 63) == 0) ws[t >> 6] = v;
  __syncthreads();
  if (t == 0) bsums[blockIdx.x] = ws[0] + ws[1] + ws[2] + ws[3];
}

// pass 2: single-block exclusive scan of block sums (nb <= 256)
__global__ __launch_bounds__(256) void k_bscan(int* __restrict__ bsums, int nb) {
  __shared__ int ws[4];
  int t = threadIdx.x;
  int lane = t & 63, w = t >> 6;
  int v = (t < nb) ? bsums[t] : 0;
  int s = v;
#pragma unroll
  for (int d = 1; d < 64; d <<= 1) {
    int u = __shfl_up(s, d, 64);
    if (lane >= d) s += u;
  }
  if (lane == 63) ws[w] = s;
  __syncthreads();
  int woff = 0;
  if (w >= 1) woff += ws[0];
  if (w >= 2) woff += ws[1];
  if (w >= 3) woff += ws[2];
  if (t < nb) bsums[t] = woff + s - v;  // exclusive
}

// pass 3: local rescan + block offset -> rowptr, cursor
__global__ __launch_bounds__(256) void k_scan2(const int* __restrict__ deg,
                                               const int* __restrict__ bsums,
                                               int* __restrict__ rowptr,
                                               int* __restrict__ cursor,
                                               int N, int E) {
  __shared__ int ws[4];
  int t = threadIdx.x;
  int lane = t & 63, w = t >> 6;
  int i = blockIdx.x * 256 + t;
  int v = (i < N) ? deg[i] : 0;
  int s = v;
#pragma unroll
  for (int d = 1; d < 64; d <<= 1) {
    int u = __shfl_up(s, d, 64);
    if (lane >= d) s += u;
  }
  if (lane == 63) ws[w] = s;
  __syncthreads();
  int woff = 0;
  if (w >= 1) woff += ws[0];
  if (w >= 2) woff += ws[1];
  if (w >= 3) woff += ws[2];
  int excl = bsums[blockIdx.x] + woff + s - v;
  if (i < N) { rowptr[i] = excl; cursor[i] = excl; }
  if (i == 0) rowptr[N] = E;
}

__global__ __launch_bounds__(256) void k_fill(const int* __restrict__ src,
                                              const int* __restrict__ dst,
                                              int* __restrict__ cursor,
                                              int* __restrict__ csr_src, int E) {
  int e = blockIdx.x * 256 + threadIdx.x;
  if (e < E) {
    int pos = atomicAdd(&cursor[dst[e]], 1);
    csr_src[pos] = src[e];
  }
}

// ---------- m = h @ W[l], bf16 MFMA; wave = 16 rows x 64 cols ----------
__global__ __launch_bounds__(256) void k_mm_mfma(const bf16* __restrict__ hbin,
                                                 const bf16* __restrict__ WTl,
                                                 bf16* __restrict__ mb,
                                                 int N, int nwaves) {
  int wid = (blockIdx.x * 256 + threadIdx.x) >> 6;
  if (wid >= nwaves) return;
  int lane = threadIdx.x & 63;
  int r = lane & 15, quad = lane >> 4, laneK = quad * 8;
  int colh = wid & 1;
  int rowt = wid >> 1;
  int row0 = rowt * 16;
  int ra = row0 + r; if (ra > N - 1) ra = N - 1;

  f32x4 acc[4];
#pragma unroll
  for (int c = 0; c < 4; c++) acc[c] = (f32x4){0.f, 0.f, 0.f, 0.f};

  const bf16* wbase = WTl + (size_t)(colh * 64) * H;
#pragma unroll
  for (int kb = 0; kb < 4; kb++) {
    int ko = kb * 32 + laneK;
    bf16x8 a = ldb8(hbin + (size_t)ra * H + ko);
#pragma unroll
    for (int c = 0; c < 4; c++) {
      bf16x8 b = ldb8(wbase + (size_t)(c * 16 + r) * H + ko);
      acc[c] = __builtin_amdgcn_mfma_f32_16x16x32_bf16(a, b, acc[c], 0, 0, 0);
    }
  }
#pragma unroll
  for (int c = 0; c < 4; c++) {
#pragma unroll
    for (int i = 0; i < 4; i++) {
      int row = row0 + quad * 4 + i;
      if (row < N) {
        int col = colh * 64 + c * 16 + r;
        mb[(size_t)row * H + col] = __float2bfloat16(acc[c][i]);
      }
    }
  }
}

// agg[n,:] = sum m[src,:]; one wave per node.
// lane = (e4, c): e4 = lane>>4 edge slot (4 edges in flight), c = lane&15
// column group (8 cols each). fp32 accumulate, cross-slot shfl reduce.
__global__ __launch_bounds__(256) void k_gather(const bf16* __restrict__ m,
                                                const int* __restrict__ rowptr,
                                                const int* __restrict__ csr_src,
                                                bf16* __restrict__ agg, int N) {
  int node = (blockIdx.x * 256 + threadIdx.x) >> 6;
  int lane = threadIdx.x & 63;
  if (node >= N) return;
  int e4 = lane >> 4;
  int c  = lane & 15;
  int b = rowptr[node], e = rowptr[node + 1];
  float acc[8];
#pragma unroll
  for (int j = 0; j < 8; j++) acc[j] = 0.f;
  for (int i = b + e4; i < e; i += 4) {
    int s = csr_src[i];
    bf16x8 v = ldb8(m + (size_t)s * H + c * 8);
#pragma unroll
    for (int j = 0; j < 8; j++) acc[j] += (float)v[j];
  }
#pragma unroll
  for (int j = 0; j < 8; j++) {
    acc[j] += __shfl_xor(acc[j], 16, 64);
    acc[j] += __shfl_xor(acc[j], 32, 64);
  }
  if (e4 == 0) {
    bf16x8 o;
#pragma unroll
    for (int j = 0; j < 8; j++) o[j] = (__bf16)acc[j];
    *(bf16x8*)(agg + (size_t)node * H + c * 8) = o;
  }
}

// ---------- fused GRU via MFMA ----------
__global__ __launch_bounds__(256) void k_gru(float* __restrict__ hf,
                                             const bf16* __restrict__ hbin,
                                             bf16* __restrict__ hbout,
                                             const bf16* __restrict__ aggb,
                                             const bf16* __restrict__ wihb,
                                             const bf16* __restrict__ whhb,
                                             const float* __restrict__ bih,
                                             const float* __restrict__ bhh,
                                             int N, int nwaves) {
  int wid = (blockIdx.x * 256 + threadIdx.x) >> 6;
  if (wid >= nwaves) return;
  int lane = threadIdx.x & 63;
  int r = lane & 15, quad = lane >> 4, laneK = quad * 8;
  int colb = wid & 7;
  int rowp = wid >> 3;
  int row0 = rowp * 32;
  if (row0 >= N) return;
  int col = colb * 16 + r;
  int ra = row0 + r;      if (ra > N - 1) ra = N - 1;
  int rb = row0 + 16 + r; if (rb > N - 1) rb = N - 1;

  f32x4 aIR[2], aIZ[2], aIN[2], aHR[2], aHZ[2], aHN[2];
#pragma unroll
  for (int t = 0; t < 2; t++) {
    aIR[t] = (f32x4){0.f,0.f,0.f,0.f}; aIZ[t] = aIR[t]; aIN[t] = aIR[t];
    aHR[t] = aIR[t]; aHZ[t] = aIR[t]; aHN[t] = aIR[t];
  }

  size_t wo0 = (size_t)(0 * H + col) * H;
  size_t wo1 = (size_t)(1 * H + col) * H;
  size_t wo2 = (size_t)(2 * H + col) * H;

#pragma unroll
  for (int kb = 0; kb < 4; kb++) {
    int ko = kb * 32 + laneK;
    bf16x8 a0 = ldb8(aggb + (size_t)ra * H + ko);
    bf16x8 a1 = ldb8(aggb + (size_t)rb * H + ko);
    bf16x8 h0 = ldb8(hbin + (size_t)ra * H + ko);
    bf16x8 h1 = ldb8(hbin + (size_t)rb * H + ko);
    bf16x8 wr = ldb8(wihb + wo0 + ko);
    aIR[0] = __builtin_amdgcn_mfma_f32_16x16x32_bf16(a0, wr, aIR[0], 0, 0, 0);
    aIR[1] = __builtin_amdgcn_mfma_f32_16x16x32_bf16(a1, wr, aIR[1], 0, 0, 0);
    bf16x8 wz = ldb8(wihb + wo1 + ko);
    aIZ[0] = __builtin_amdgcn_mfma_f32_16x16x32_bf16(a0, wz, aIZ[0], 0, 0, 0);
    aIZ[1] = __builtin_amdgcn_mfma_f32_16x16x32_bf16(a1, wz, aIZ[1], 0, 0, 0);
    bf16x8 wn = ldb8(wihb + wo2 + ko);
    aIN[0] = __builtin_amdgcn_mfma_f32_16x16x32_bf16(a0, wn, aIN[0], 0, 0, 0);
    aIN[1] = __builtin_amdgcn_mfma_f32_16x16x32_bf16(a1, wn, aIN[1], 0, 0, 0);
    bf16x8 ur = ldb8(whhb + wo0 + ko);
    aHR[0] = __builtin_amdgcn_mfma_f32_16x16x32_bf16(h0, ur, aHR[0], 0, 0, 0);
    aHR[1] = __builtin_amdgcn_mfma_f32_16x16x32_bf16(h1, ur, aHR[1], 0, 0, 0);
    bf16x8 uz = ldb8(whhb + wo1 + ko);
    aHZ[0] = __builtin_amdgcn_mfma_f32_16x16x32_bf16(h0, uz, aHZ[0], 0, 0, 0);
    aHZ[1] = __builtin_amdgcn_mfma_f32_16x16x32_bf16(h1, uz, aHZ[1], 0, 0, 0);
    bf16x8 un = ldb8(whhb + wo2 + ko);
    aHN[0] = __builtin_amdgcn_mfma_f32_16x16x32_bf16(h0, un, aHN[0], 0, 0, 0);
    aHN[1] = __builtin_amdgcn_mfma_f32_16x16x32_bf16(h1, un, aHN[1], 0, 0, 0);
  }

  float bir = bih[col], biz = bih[H + col], bin = bih[2 * H + col];
  float bhr = bhh[col], bhz = bhh[H + col], bhn = bhh[2 * H + col];
#pragma unroll
  for (int t = 0; t < 2; t++) {
#pragma unroll
    for (int i = 0; i < 4; i++) {
      int row = row0 + t * 16 + quad * 4 + i;
      if (row < N) {
        float rg = 1.f / (1.f + expf(-(aIR[t][i] + bir + aHR[t][i] + bhr)));
        float zg = 1.f / (1.f + expf(-(aIZ[t][i] + biz + aHZ[t][i] + bhz)));
        float ng = tanhf(aIN[t][i] + bin + rg * (aHN[t][i] + bhn));
        size_t o = (size_t)row * H + col;
        float hold = hf[o];
        float hp = (1.f - zg) * ng + zg * hold;
        hf[o] = hp;
        hbout[o] = __float2bfloat16(hp);
      }
    }
  }
}

// out[n,:] = log_softmax(h[n,:] @ lin_w^T + lin_b); one wave per node
__global__ __launch_bounds__(256) void k_classify(const float* __restrict__ h,
                                                  const float* __restrict__ lw,
                                                  const float* __restrict__ lb,
                                                  float* __restrict__ out, int N) {
  int wave = (blockIdx.x * 256 + threadIdx.x) >> 6;
  int lane = threadIdx.x & 63;
  if (wave >= N) return;
  int c = lane & 15;
  int q = lane >> 4;
  const float* hr = h + (size_t)wave * H + q * 32;
  const float* wr = lw + c * H + q * 32;
  float p = 0.f;
#pragma unroll
  for (int k = 0; k < 32; k += 4) {
    float4 a = *(const float4*)(hr + k);
    float4 w = *(const float4*)(wr + k);
    p += a.x * w.x + a.y * w.y + a.z * w.z + a.w * w.w;
  }
  p += __shfl_xor(p, 16, 64);
  p += __shfl_xor(p, 32, 64);
  float z = p + lb[c];
  float mx = z;
#pragma unroll
  for (int d = 1; d < 16; d <<= 1) mx = fmaxf(mx, __shfl_xor(mx, d, 64));
  float e = expf(z - mx);
  float s = e;
#pragma unroll
  for (int d = 1; d < 16; d <<= 1) s += __shfl_xor(s, d, 64);
  if (q == 0) out[(size_t)wave * 16 + c] = z - mx - logf(s);
}

extern "C" void kernel_launch(void* const* d_in, const int* in_sizes, int n_in,
                              void* d_out, int out_size, void* d_ws, size_t ws_size,
                              hipStream_t stream) {
  const float* x   = (const float*)d_in[0];
  const int*   ei  = (const int*)d_in[1];
  const float* W   = (const float*)d_in[2];
  const float* wih = (const float*)d_in[3];
  const float* whh = (const float*)d_in[4];
  const float* bih = (const float*)d_in[5];
  const float* bhh = (const float*)d_in[6];
  const float* lw  = (const float*)d_in[7];
  const float* lb  = (const float*)d_in[8];
  float* out = (float*)d_out;

  int N = in_sizes[0] / 64;   // 50000
  int E = in_sizes[1] / 2;    // 800000
  const int* src = ei;
  const int* dst = ei + E;

  size_t NH = (size_t)N * H;
  float* hf  = (float*)d_ws;                 // [N,H] fp32 canonical h
  bf16* hb0  = (bf16*)(hf + NH);             // [N,H] bf16 h ping
  bf16* hb1  = hb0 + NH;                     // [N,H] bf16 h pong
  bf16* mb   = hb1 + NH;                     // [N,H] bf16 m
  bf16* aggb = mb + NH;                      // [N,H] bf16 agg
  bf16* WTb  = aggb + NH;                    // [3,H,H]
  bf16* wihb = WTb + 3 * H * H;              // [3H,H]
  bf16* whhb = wihb + 3 * H * H;             // [3H,H]
  int* deg     = (int*)(whhb + 3 * H * H);
  int* rowptr  = deg + N;                    // N+1
  int* cursor  = rowptr + N + 1;             // N
  int* bsums   = cursor + N;                 // <=256
  int* csr_src = bsums + 256;                // E

  int nb_nh = (int)((NH + 255) / 256);
  int nb_e  = (E + 255) / 256;
  int nb_w  = (3 * H * H + 255) / 256;
  int nb_n  = (N + 255) / 256;               // 196 blocks

  int rowtiles = (N + 15) / 16;              // 3125
  int nw_mm = rowtiles * 2;
  int nb_mm = (nw_mm * 64 + 255) / 256;
  int rowpairs = (rowtiles + 1) / 2;
  int nw_gru = rowpairs * 8;
  int nb_gru = (nw_gru * 64 + 255) / 256;
  int nb_ga = (int)(((size_t)N * 64 + 255) / 256);

  k_init_h<<<nb_nh, 256, 0, stream>>>(x, hf, hb0, N);
  k_cvtW<<<nb_w, 256, 0, stream>>>(W, WTb);
  k_cvt<<<nb_w, 256, 0, stream>>>(wih, wihb, 3 * H * H);
  k_cvt<<<nb_w, 256, 0, stream>>>(whh, whhb, 3 * H * H);

  // CSR build (parallel scan)
  hipMemsetAsync(deg, 0, (size_t)N * sizeof(int), stream);
  k_count<<<nb_e, 256, 0, stream>>>(dst, deg, E);
  k_bsum<<<nb_n, 256, 0, stream>>>(deg, bsums, N);
  k_bscan<<<1, 256, 0, stream>>>(bsums, nb_n);
  k_scan2<<<nb_n, 256, 0, stream>>>(deg, bsums, rowptr, cursor, N, E);
  k_fill<<<nb_e, 256, 0, stream>>>(src, dst, cursor, csr_src, E);

  bf16* hbp[2] = {hb0, hb1};
  for (int l = 0; l < 3; l++) {
    bf16* hin  = hbp[l & 1];
    bf16* hout = hbp[(l + 1) & 1];
    k_mm_mfma<<<nb_mm, 256, 0, stream>>>(hin, WTb + (size_t)l * H * H, mb, N, nw_mm);
    k_gather<<<nb_ga, 256, 0, stream>>>(mb, rowptr, csr_src, aggb, N);
    k_gru<<<nb_gru, 256, 0, stream>>>(hf, hin, hout, aggb, wihb, whhb,
                                      bih, bhh, N, nw_gru);
  }

  k_classify<<<(N + 3) / 4, 256, 0, stream>>>(hf, lw, lb, out, N);
}

// Round 5
// 587.611 us; speedup vs baseline: 9.3609x; 1.0620x over previous
//
#include <hip/hip_runtime.h>
#include <hip/hip_bf16.h>
#include <math.h>

#define H 128

typedef __bf16 bf16x8 __attribute__((ext_vector_type(8)));
typedef float f32x4 __attribute__((ext_vector_type(4)));
typedef __hip_bfloat16 bf16;

__device__ __forceinline__ bf16x8 ldb8(const bf16* p) {
  return *(const bf16x8*)(const void*)p;
}
__device__ __forceinline__ float fsig(float x) {
  return __fdividef(1.f, 1.f + __expf(-x));
}
__device__ __forceinline__ float ftanh(float x) {
  float x2 = fminf(fmaxf(2.f * x, -80.f), 80.f);
  float t = __expf(x2);
  return __fdividef(t - 1.f, t + 1.f);
}

// h0[n,f] = f<64 ? x[n,f] : 0   (bf16)
__global__ __launch_bounds__(256) void k_init_h(const float* __restrict__ x,
                                                bf16* __restrict__ hb, int N) {
  int i = blockIdx.x * 256 + threadIdx.x;
  if (i < N * H) {
    int f = i & (H - 1);
    int n = i >> 7;
    hb[i] = __float2bfloat16((f < 64) ? x[n * 64 + f] : 0.f);
  }
}

__global__ __launch_bounds__(256) void k_cvt(const float* __restrict__ in,
                                             bf16* __restrict__ out, int n) {
  int i = blockIdx.x * 256 + threadIdx.x;
  if (i < n) out[i] = __float2bfloat16(in[i]);
}

// G[l][j][k] = sum_t w_ih[j][t] * W[l][k][t]   (fp32 math, bf16 out)
__global__ __launch_bounds__(256) void k_G(const float* __restrict__ W,
                                           const float* __restrict__ wih,
                                           bf16* __restrict__ G) {
  int idx = blockIdx.x * 256 + threadIdx.x;
  if (idx >= 3 * 3 * H * H) return;
  int l = idx / (3 * H * H);
  int r = idx % (3 * H * H);
  int j = r >> 7;          // 0..383 (gate*H + col)
  int k = r & (H - 1);
  const float4* a = (const float4*)(wih + (size_t)j * H);
  const float4* b = (const float4*)(W + (size_t)l * H * H + (size_t)k * H);
  float s = 0.f;
#pragma unroll
  for (int q = 0; q < 32; q++) {
    float4 av = a[q], bv = b[q];
    s += av.x * bv.x + av.y * bv.y + av.z * bv.z + av.w * bv.w;
  }
  G[idx] = __float2bfloat16(s);
}

// ---------- CSR build ----------
__global__ __launch_bounds__(256) void k_count(const int* __restrict__ dst,
                                               int* __restrict__ deg, int E) {
  int e = blockIdx.x * 256 + threadIdx.x;
  if (e < E) atomicAdd(&deg[dst[e]], 1);
}

__global__ __launch_bounds__(256) void k_bsum(const int* __restrict__ deg,
                                              int* __restrict__ bsums, int N) {
  __shared__ int ws[4];
  int t = threadIdx.x;
  int i = blockIdx.x * 256 + t;
  int v = (i < N) ? deg[i] : 0;
#pragma unroll
  for (int d = 1; d < 64; d <<= 1) v += __shfl_xor(v, d, 64);
  if ((t & 63) == 0) ws[t >> 6] = v;
  __syncthreads();
  if (t == 0) bsums[blockIdx.x] = ws[0] + ws[1] + ws[2] + ws[3];
}

__global__ __launch_bounds__(256) void k_bscan(int* __restrict__ bsums, int nb) {
  __shared__ int ws[4];
  int t = threadIdx.x;
  int lane = t & 63, w = t >> 6;
  int v = (t < nb) ? bsums[t] : 0;
  int s = v;
#pragma unroll
  for (int d = 1; d < 64; d <<= 1) {
    int u = __shfl_up(s, d, 64);
    if (lane >= d) s += u;
  }
  if (lane == 63) ws[w] = s;
  __syncthreads();
  int woff = 0;
  if (w >= 1) woff += ws[0];
  if (w >= 2) woff += ws[1];
  if (w >= 3) woff += ws[2];
  if (t < nb) bsums[t] = woff + s - v;
}

__global__ __launch_bounds__(256) void k_scan2(const int* __restrict__ deg,
                                               const int* __restrict__ bsums,
                                               int* __restrict__ rowptr,
                                               int* __restrict__ cursor,
                                               int N, int E) {
  __shared__ int ws[4];
  int t = threadIdx.x;
  int lane = t & 63, w = t >> 6;
  int i = blockIdx.x * 256 + t;
  int v = (i < N) ? deg[i] : 0;
  int s = v;
#pragma unroll
  for (int d = 1; d < 64; d <<= 1) {
    int u = __shfl_up(s, d, 64);
    if (lane >= d) s += u;
  }
  if (lane == 63) ws[w] = s;
  __syncthreads();
  int woff = 0;
  if (w >= 1) woff += ws[0];
  if (w >= 2) woff += ws[1];
  if (w >= 3) woff += ws[2];
  int excl = bsums[blockIdx.x] + woff + s - v;
  if (i < N) { rowptr[i] = excl; cursor[i] = excl; }
  if (i == 0) rowptr[N] = E;
}

__global__ __launch_bounds__(256) void k_fill(const int* __restrict__ src,
                                              const int* __restrict__ dst,
                                              int* __restrict__ cursor,
                                              int* __restrict__ csr_src, int E) {
  int e = blockIdx.x * 256 + threadIdx.x;
  if (e < E) {
    int pos = atomicAdd(&cursor[dst[e]], 1);
    csr_src[pos] = src[e];
  }
}

// ---------- fused layer: gather A = segsum(h[src]) into LDS, then GRU ----------
// block = 512 threads = 8 waves, owns 32 rows.
// gather: wave w handles rows 4w..4w+3; lane=(e4,c) 4 edge slots x 16 colgroups
// GRU: wave w = col-group w (16 cols); 32 rows x 16 cols per wave;
//      gi = A @ G (A from LDS), gh = h @ whh (global), epilogue in regs.
#define ASTRIDE 136   // 128 + 8 bf16 pad: b128 LDS reads 2-way conflict only
__global__ __launch_bounds__(512) void k_layer(const bf16* __restrict__ hbin,
                                               bf16* __restrict__ hbout,
                                               float* __restrict__ hf,  // may be null
                                               const bf16* __restrict__ Gl,
                                               const bf16* __restrict__ whhb,
                                               const float* __restrict__ bih,
                                               const float* __restrict__ bhh,
                                               const int* __restrict__ rowptr,
                                               const int* __restrict__ csr_src,
                                               int N) {
  __shared__ bf16 As[32 * ASTRIDE];
  int t = threadIdx.x;
  int w = t >> 6;
  int lane = t & 63;
  int row0 = blockIdx.x * 32;

  // ---- gather phase ----
  {
    int e4 = lane >> 4;
    int c = lane & 15;
    for (int rr = 0; rr < 4; rr++) {
      int rl = w * 4 + rr;          // local row 0..31
      int row = row0 + rl;
      float acc[8];
#pragma unroll
      for (int j = 0; j < 8; j++) acc[j] = 0.f;
      if (row < N) {
        int b = rowptr[row], e = rowptr[row + 1];
        for (int i = b + e4; i < e; i += 4) {
          int s = csr_src[i];
          bf16x8 v = ldb8(hbin + (size_t)s * H + c * 8);
#pragma unroll
          for (int j = 0; j < 8; j++) acc[j] += (float)v[j];
        }
      }
#pragma unroll
      for (int j = 0; j < 8; j++) {
        acc[j] += __shfl_xor(acc[j], 16, 64);
        acc[j] += __shfl_xor(acc[j], 32, 64);
      }
      if (e4 == 0) {
        bf16x8 o;
#pragma unroll
        for (int j = 0; j < 8; j++) o[j] = (__bf16)acc[j];
        *(bf16x8*)(&As[rl * ASTRIDE + c * 8]) = o;
      }
    }
  }
  __syncthreads();

  // ---- GRU phase ----
  int r = lane & 15, quad = lane >> 4, laneK = quad * 8;
  int col = w * 16 + r;
  int ra = row0 + r;      if (ra > N - 1) ra = N - 1;
  int rb = row0 + 16 + r; if (rb > N - 1) rb = N - 1;

  f32x4 aIR[2], aIZ[2], aIN[2], aHR[2], aHZ[2], aHN[2];
#pragma unroll
  for (int q = 0; q < 2; q++) {
    aIR[q] = (f32x4){0.f, 0.f, 0.f, 0.f};
    aIZ[q] = aIR[q]; aIN[q] = aIR[q];
    aHR[q] = aIR[q]; aHZ[q] = aIR[q]; aHN[q] = aIR[q];
  }

  size_t wo0 = (size_t)(0 * H + col) * H;
  size_t wo1 = (size_t)(1 * H + col) * H;
  size_t wo2 = (size_t)(2 * H + col) * H;

#pragma unroll
  for (int kb = 0; kb < 4; kb++) {
    int ko = kb * 32 + laneK;
    bf16x8 a0 = *(const bf16x8*)(&As[r * ASTRIDE + ko]);
    bf16x8 a1 = *(const bf16x8*)(&As[(16 + r) * ASTRIDE + ko]);
    bf16x8 h0 = ldb8(hbin + (size_t)ra * H + ko);
    bf16x8 h1 = ldb8(hbin + (size_t)rb * H + ko);
    bf16x8 gr = ldb8(Gl + wo0 + ko);
    aIR[0] = __builtin_amdgcn_mfma_f32_16x16x32_bf16(a0, gr, aIR[0], 0, 0, 0);
    aIR[1] = __builtin_amdgcn_mfma_f32_16x16x32_bf16(a1, gr, aIR[1], 0, 0, 0);
    bf16x8 gz = ldb8(Gl + wo1 + ko);
    aIZ[0] = __builtin_amdgcn_mfma_f32_16x16x32_bf16(a0, gz, aIZ[0], 0, 0, 0);
    aIZ[1] = __builtin_amdgcn_mfma_f32_16x16x32_bf16(a1, gz, aIZ[1], 0, 0, 0);
    bf16x8 gn = ldb8(Gl + wo2 + ko);
    aIN[0] = __builtin_amdgcn_mfma_f32_16x16x32_bf16(a0, gn, aIN[0], 0, 0, 0);
    aIN[1] = __builtin_amdgcn_mfma_f32_16x16x32_bf16(a1, gn, aIN[1], 0, 0, 0);
    bf16x8 ur = ldb8(whhb + wo0 + ko);
    aHR[0] = __builtin_amdgcn_mfma_f32_16x16x32_bf16(h0, ur, aHR[0], 0, 0, 0);
    aHR[1] = __builtin_amdgcn_mfma_f32_16x16x32_bf16(h1, ur, aHR[1], 0, 0, 0);
    bf16x8 uz = ldb8(whhb + wo1 + ko);
    aHZ[0] = __builtin_amdgcn_mfma_f32_16x16x32_bf16(h0, uz, aHZ[0], 0, 0, 0);
    aHZ[1] = __builtin_amdgcn_mfma_f32_16x16x32_bf16(h1, uz, aHZ[1], 0, 0, 0);
    bf16x8 un = ldb8(whhb + wo2 + ko);
    aHN[0] = __builtin_amdgcn_mfma_f32_16x16x32_bf16(h0, un, aHN[0], 0, 0, 0);
    aHN[1] = __builtin_amdgcn_mfma_f32_16x16x32_bf16(h1, un, aHN[1], 0, 0, 0);
  }

  float bir = bih[col], biz = bih[H + col], bin = bih[2 * H + col];
  float bhr = bhh[col], bhz = bhh[H + col], bhn = bhh[2 * H + col];
#pragma unroll
  for (int q = 0; q < 2; q++) {
#pragma unroll
    for (int i = 0; i < 4; i++) {
      int row = row0 + q * 16 + quad * 4 + i;
      if (row < N) {
        float rg = fsig(aIR[q][i] + bir + aHR[q][i] + bhr);
        float zg = fsig(aIZ[q][i] + biz + aHZ[q][i] + bhz);
        float ng = ftanh(aIN[q][i] + bin + rg * (aHN[q][i] + bhn));
        size_t o = (size_t)row * H + col;
        float hold = __bfloat162float(hbin[o]);
        float hp = (1.f - zg) * ng + zg * hold;
        hbout[o] = __float2bfloat16(hp);
        if (hf) hf[o] = hp;
      }
    }
  }
}

// out[n,:] = log_softmax(h[n,:] @ lin_w^T + lin_b); one wave per node (fp32 h)
__global__ __launch_bounds__(256) void k_classify(const float* __restrict__ h,
                                                  const float* __restrict__ lw,
                                                  const float* __restrict__ lb,
                                                  float* __restrict__ out, int N) {
  int wave = (blockIdx.x * 256 + threadIdx.x) >> 6;
  int lane = threadIdx.x & 63;
  if (wave >= N) return;
  int c = lane & 15;
  int q = lane >> 4;
  const float* hr = h + (size_t)wave * H + q * 32;
  const float* wr = lw + c * H + q * 32;
  float p = 0.f;
#pragma unroll
  for (int k = 0; k < 32; k += 4) {
    float4 a = *(const float4*)(hr + k);
    float4 w = *(const float4*)(wr + k);
    p += a.x * w.x + a.y * w.y + a.z * w.z + a.w * w.w;
  }
  p += __shfl_xor(p, 16, 64);
  p += __shfl_xor(p, 32, 64);
  float z = p + lb[c];
  float mx = z;
#pragma unroll
  for (int d = 1; d < 16; d <<= 1) mx = fmaxf(mx, __shfl_xor(mx, d, 64));
  float e = expf(z - mx);
  float s = e;
#pragma unroll
  for (int d = 1; d < 16; d <<= 1) s += __shfl_xor(s, d, 64);
  if (q == 0) out[(size_t)wave * 16 + c] = z - mx - logf(s);
}

extern "C" void kernel_launch(void* const* d_in, const int* in_sizes, int n_in,
                              void* d_out, int out_size, void* d_ws, size_t ws_size,
                              hipStream_t stream) {
  const float* x   = (const float*)d_in[0];
  const int*   ei  = (const int*)d_in[1];
  const float* W   = (const float*)d_in[2];
  const float* wih = (const float*)d_in[3];
  const float* whh = (const float*)d_in[4];
  const float* bih = (const float*)d_in[5];
  const float* bhh = (const float*)d_in[6];
  const float* lw  = (const float*)d_in[7];
  const float* lb  = (const float*)d_in[8];
  float* out = (float*)d_out;

  int N = in_sizes[0] / 64;   // 50000
  int E = in_sizes[1] / 2;    // 800000
  const int* src = ei;
  const int* dst = ei + E;

  size_t NH = (size_t)N * H;
  float* hf  = (float*)d_ws;                 // [N,H] fp32 final h (layer 3 only)
  bf16* hb0  = (bf16*)(hf + NH);             // [N,H] bf16 h ping
  bf16* hb1  = hb0 + NH;                     // [N,H] bf16 h pong
  bf16* Gb   = hb1 + NH;                     // [3][3H,H] fused input-side weights
  bf16* whhb = Gb + 3 * 3 * H * H;           // [3H,H]
  int* deg     = (int*)(whhb + 3 * H * H);
  int* rowptr  = deg + N;                    // N+1
  int* cursor  = rowptr + N + 1;             // N
  int* bsums   = cursor + N;                 // <=256
  int* csr_src = bsums + 256;                // E

  int nb_nh = (int)((NH + 255) / 256);
  int nb_e  = (E + 255) / 256;
  int nb_n  = (N + 255) / 256;

  k_init_h<<<nb_nh, 256, 0, stream>>>(x, hb0, N);
  k_cvt<<<(3 * H * H + 255) / 256, 256, 0, stream>>>(whh, whhb, 3 * H * H);
  k_G<<<(3 * 3 * H * H + 255) / 256, 256, 0, stream>>>(W, wih, Gb);

  // CSR build
  hipMemsetAsync(deg, 0, (size_t)N * sizeof(int), stream);
  k_count<<<nb_e, 256, 0, stream>>>(dst, deg, E);
  k_bsum<<<nb_n, 256, 0, stream>>>(deg, bsums, N);
  k_bscan<<<1, 256, 0, stream>>>(bsums, nb_n);
  k_scan2<<<nb_n, 256, 0, stream>>>(deg, bsums, rowptr, cursor, N, E);
  k_fill<<<nb_e, 256, 0, stream>>>(src, dst, cursor, csr_src, E);

  int nb_layer = (N + 31) / 32;   // 1563 blocks of 512
  bf16* hbp[2] = {hb0, hb1};
  for (int l = 0; l < 3; l++) {
    bf16* hin  = hbp[l & 1];
    bf16* hout = hbp[(l + 1) & 1];
    k_layer<<<nb_layer, 512, 0, stream>>>(hin, hout, (l == 2) ? hf : nullptr,
                                          Gb + (size_t)l * 3 * H * H, whhb,
                                          bih, bhh, rowptr, csr_src, N);
  }

  k_classify<<<(N + 3) / 4, 256, 0, stream>>>(hf, lw, lb, out, N);
}

// Round 6
// 518.926 us; speedup vs baseline: 10.5999x; 1.1324x over previous
//
#include <hip/hip_runtime.h>
#include <hip/hip_bf16.h>
#include <math.h>

#define H 128

typedef __bf16 bf16x8 __attribute__((ext_vector_type(8)));
typedef float f32x4 __attribute__((ext_vector_type(4)));
typedef __hip_bfloat16 bf16;

__device__ __forceinline__ bf16x8 ldb8(const bf16* p) {
  return *(const bf16x8*)(const void*)p;
}
__device__ __forceinline__ float fsig(float x) {
  return __fdividef(1.f, 1.f + __expf(-x));
}
__device__ __forceinline__ float ftanh(float x) {
  float x2 = fminf(fmaxf(2.f * x, -80.f), 80.f);
  float t = __expf(x2);
  return __fdividef(t - 1.f, t + 1.f);
}

// h0[n,f] = f<64 ? x[n,f] : 0   (bf16)
__global__ __launch_bounds__(256) void k_init_h(const float* __restrict__ x,
                                                bf16* __restrict__ hb, int N) {
  int i = blockIdx.x * 256 + threadIdx.x;
  if (i < N * H) {
    int f = i & (H - 1);
    int n = i >> 7;
    hb[i] = __float2bfloat16((f < 64) ? x[n * 64 + f] : 0.f);
  }
}

__global__ __launch_bounds__(256) void k_cvt(const float* __restrict__ in,
                                             bf16* __restrict__ out, int n) {
  int i = blockIdx.x * 256 + threadIdx.x;
  if (i < n) out[i] = __float2bfloat16(in[i]);
}

// G[l][j][k] = sum_t w_ih[j][t] * W[l][k][t]   (fp32 math, bf16 out)
__global__ __launch_bounds__(256) void k_G(const float* __restrict__ W,
                                           const float* __restrict__ wih,
                                           bf16* __restrict__ G) {
  int idx = blockIdx.x * 256 + threadIdx.x;
  if (idx >= 3 * 3 * H * H) return;
  int l = idx / (3 * H * H);
  int r = idx % (3 * H * H);
  int j = r >> 7;
  int k = r & (H - 1);
  const float4* a = (const float4*)(wih + (size_t)j * H);
  const float4* b = (const float4*)(W + (size_t)l * H * H + (size_t)k * H);
  float s = 0.f;
#pragma unroll
  for (int q = 0; q < 32; q++) {
    float4 av = a[q], bv = b[q];
    s += av.x * bv.x + av.y * bv.y + av.z * bv.z + av.w * bv.w;
  }
  G[idx] = __float2bfloat16(s);
}

// ---------- CSR build ----------
__global__ __launch_bounds__(256) void k_count(const int* __restrict__ dst,
                                               int* __restrict__ deg, int E) {
  int e = blockIdx.x * 256 + threadIdx.x;
  if (e < E) atomicAdd(&deg[dst[e]], 1);
}

__global__ __launch_bounds__(256) void k_bsum(const int* __restrict__ deg,
                                              int* __restrict__ bsums, int N) {
  __shared__ int ws[4];
  int t = threadIdx.x;
  int i = blockIdx.x * 256 + t;
  int v = (i < N) ? deg[i] : 0;
#pragma unroll
  for (int d = 1; d < 64; d <<= 1) v += __shfl_xor(v, d, 64);
  if ((t & 63) == 0) ws[t >> 6] = v;
  __syncthreads();
  if (t == 0) bsums[blockIdx.x] = ws[0] + ws[1] + ws[2] + ws[3];
}

__global__ __launch_bounds__(256) void k_bscan(int* __restrict__ bsums, int nb) {
  __shared__ int ws[4];
  int t = threadIdx.x;
  int lane = t & 63, w = t >> 6;
  int v = (t < nb) ? bsums[t] : 0;
  int s = v;
#pragma unroll
  for (int d = 1; d < 64; d <<= 1) {
    int u = __shfl_up(s, d, 64);
    if (lane >= d) s += u;
  }
  if (lane == 63) ws[w] = s;
  __syncthreads();
  int woff = 0;
  if (w >= 1) woff += ws[0];
  if (w >= 2) woff += ws[1];
  if (w >= 3) woff += ws[2];
  if (t < nb) bsums[t] = woff + s - v;
}

__global__ __launch_bounds__(256) void k_scan2(const int* __restrict__ deg,
                                               const int* __restrict__ bsums,
                                               int* __restrict__ rowptr,
                                               int* __restrict__ cursor,
                                               int N, int E) {
  __shared__ int ws[4];
  int t = threadIdx.x;
  int lane = t & 63, w = t >> 6;
  int i = blockIdx.x * 256 + t;
  int v = (i < N) ? deg[i] : 0;
  int s = v;
#pragma unroll
  for (int d = 1; d < 64; d <<= 1) {
    int u = __shfl_up(s, d, 64);
    if (lane >= d) s += u;
  }
  if (lane == 63) ws[w] = s;
  __syncthreads();
  int woff = 0;
  if (w >= 1) woff += ws[0];
  if (w >= 2) woff += ws[1];
  if (w >= 3) woff += ws[2];
  int excl = bsums[blockIdx.x] + woff + s - v;
  if (i < N) { rowptr[i] = excl; cursor[i] = excl; }
  if (i == 0) rowptr[N] = E;
}

__global__ __launch_bounds__(256) void k_fill(const int* __restrict__ src,
                                              const int* __restrict__ dst,
                                              int* __restrict__ cursor,
                                              int* __restrict__ csr_src, int E) {
  int e = blockIdx.x * 256 + threadIdx.x;
  if (e < E) {
    int pos = atomicAdd(&cursor[dst[e]], 1);
    csr_src[pos] = src[e];
  }
}

// ---------- fused layer: gather A = segsum(h[src]) into LDS, then GRU ----------
// block = 512 threads = 8 waves, owns 32 rows.
#define ASTRIDE 136   // 128 + 8 bf16 pad
__global__ __launch_bounds__(512) void k_layer(const bf16* __restrict__ hbin,
                                               bf16* __restrict__ hbout,
                                               float* __restrict__ hf,  // may be null
                                               const bf16* __restrict__ Gl,
                                               const bf16* __restrict__ whhb,
                                               const float* __restrict__ bih,
                                               const float* __restrict__ bhh,
                                               const int* __restrict__ rowptr,
                                               const int* __restrict__ csr_src,
                                               int N) {
  __shared__ bf16 As[32 * ASTRIDE];
  __shared__ bf16 Hs[32 * ASTRIDE];
  int t = threadIdx.x;
  int w = t >> 6;
  int lane = t & 63;
  int row0 = blockIdx.x * 32;

  // ---- stage own h rows (coalesced): thread t -> row t>>4, chunk t&15 ----
  {
    int rl = t >> 4;
    int c = t & 15;
    int row = row0 + rl; if (row > N - 1) row = N - 1;
    bf16x8 v = ldb8(hbin + (size_t)row * H + c * 8);
    *(bf16x8*)(&Hs[rl * ASTRIDE + c * 8]) = v;
  }

  // ---- gather phase (2-way unrolled edge loop) ----
  {
    int e4 = lane >> 4;
    int c = lane & 15;
    for (int rr = 0; rr < 4; rr++) {
      int rl = w * 4 + rr;
      int row = row0 + rl;
      float acc[8];
#pragma unroll
      for (int j = 0; j < 8; j++) acc[j] = 0.f;
      if (row < N) {
        int b = rowptr[row], e = rowptr[row + 1];
        int i = b + e4;
        for (; i + 4 < e; i += 8) {
          int s0 = csr_src[i];
          int s1 = csr_src[i + 4];
          bf16x8 v0 = ldb8(hbin + (size_t)s0 * H + c * 8);
          bf16x8 v1 = ldb8(hbin + (size_t)s1 * H + c * 8);
#pragma unroll
          for (int j = 0; j < 8; j++) acc[j] += (float)v0[j] + (float)v1[j];
        }
        if (i < e) {
          int s0 = csr_src[i];
          bf16x8 v0 = ldb8(hbin + (size_t)s0 * H + c * 8);
#pragma unroll
          for (int j = 0; j < 8; j++) acc[j] += (float)v0[j];
        }
      }
#pragma unroll
      for (int j = 0; j < 8; j++) {
        acc[j] += __shfl_xor(acc[j], 16, 64);
        acc[j] += __shfl_xor(acc[j], 32, 64);
      }
      if (e4 == 0) {
        bf16x8 o;
#pragma unroll
        for (int j = 0; j < 8; j++) o[j] = (__bf16)acc[j];
        *(bf16x8*)(&As[rl * ASTRIDE + c * 8]) = o;
      }
    }
  }
  __syncthreads();

  // ---- GRU phase (A and h from LDS) ----
  int r = lane & 15, quad = lane >> 4, laneK = quad * 8;
  int col = w * 16 + r;

  f32x4 aIR[2], aIZ[2], aIN[2], aHR[2], aHZ[2], aHN[2];
#pragma unroll
  for (int q = 0; q < 2; q++) {
    aIR[q] = (f32x4){0.f, 0.f, 0.f, 0.f};
    aIZ[q] = aIR[q]; aIN[q] = aIR[q];
    aHR[q] = aIR[q]; aHZ[q] = aIR[q]; aHN[q] = aIR[q];
  }

  size_t wo0 = (size_t)(0 * H + col) * H;
  size_t wo1 = (size_t)(1 * H + col) * H;
  size_t wo2 = (size_t)(2 * H + col) * H;

#pragma unroll
  for (int kb = 0; kb < 4; kb++) {
    int ko = kb * 32 + laneK;
    bf16x8 a0 = *(const bf16x8*)(&As[r * ASTRIDE + ko]);
    bf16x8 a1 = *(const bf16x8*)(&As[(16 + r) * ASTRIDE + ko]);
    bf16x8 h0 = *(const bf16x8*)(&Hs[r * ASTRIDE + ko]);
    bf16x8 h1 = *(const bf16x8*)(&Hs[(16 + r) * ASTRIDE + ko]);
    bf16x8 gr = ldb8(Gl + wo0 + ko);
    aIR[0] = __builtin_amdgcn_mfma_f32_16x16x32_bf16(a0, gr, aIR[0], 0, 0, 0);
    aIR[1] = __builtin_amdgcn_mfma_f32_16x16x32_bf16(a1, gr, aIR[1], 0, 0, 0);
    bf16x8 gz = ldb8(Gl + wo1 + ko);
    aIZ[0] = __builtin_amdgcn_mfma_f32_16x16x32_bf16(a0, gz, aIZ[0], 0, 0, 0);
    aIZ[1] = __builtin_amdgcn_mfma_f32_16x16x32_bf16(a1, gz, aIZ[1], 0, 0, 0);
    bf16x8 gn = ldb8(Gl + wo2 + ko);
    aIN[0] = __builtin_amdgcn_mfma_f32_16x16x32_bf16(a0, gn, aIN[0], 0, 0, 0);
    aIN[1] = __builtin_amdgcn_mfma_f32_16x16x32_bf16(a1, gn, aIN[1], 0, 0, 0);
    bf16x8 ur = ldb8(whhb + wo0 + ko);
    aHR[0] = __builtin_amdgcn_mfma_f32_16x16x32_bf16(h0, ur, aHR[0], 0, 0, 0);
    aHR[1] = __builtin_amdgcn_mfma_f32_16x16x32_bf16(h1, ur, aHR[1], 0, 0, 0);
    bf16x8 uz = ldb8(whhb + wo1 + ko);
    aHZ[0] = __builtin_amdgcn_mfma_f32_16x16x32_bf16(h0, uz, aHZ[0], 0, 0, 0);
    aHZ[1] = __builtin_amdgcn_mfma_f32_16x16x32_bf16(h1, uz, aHZ[1], 0, 0, 0);
    bf16x8 un = ldb8(whhb + wo2 + ko);
    aHN[0] = __builtin_amdgcn_mfma_f32_16x16x32_bf16(h0, un, aHN[0], 0, 0, 0);
    aHN[1] = __builtin_amdgcn_mfma_f32_16x16x32_bf16(h1, un, aHN[1], 0, 0, 0);
  }

  float bir = bih[col], biz = bih[H + col], bin = bih[2 * H + col];
  float bhr = bhh[col], bhz = bhh[H + col], bhn = bhh[2 * H + col];
#pragma unroll
  for (int q = 0; q < 2; q++) {
#pragma unroll
    for (int i = 0; i < 4; i++) {
      int lrow = q * 16 + quad * 4 + i;
      int row = row0 + lrow;
      if (row < N) {
        float rg = fsig(aIR[q][i] + bir + aHR[q][i] + bhr);
        float zg = fsig(aIZ[q][i] + biz + aHZ[q][i] + bhz);
        float ng = ftanh(aIN[q][i] + bin + rg * (aHN[q][i] + bhn));
        float hold = __bfloat162float(Hs[lrow * ASTRIDE + col]);
        float hp = (1.f - zg) * ng + zg * hold;
        size_t o = (size_t)row * H + col;
        hbout[o] = __float2bfloat16(hp);
        if (hf) hf[o] = hp;
      }
    }
  }
}

// out[n,:] = log_softmax(h[n,:] @ lin_w^T + lin_b); one wave per node (fp32 h)
__global__ __launch_bounds__(256) void k_classify(const float* __restrict__ h,
                                                  const float* __restrict__ lw,
                                                  const float* __restrict__ lb,
                                                  float* __restrict__ out, int N) {
  int wave = (blockIdx.x * 256 + threadIdx.x) >> 6;
  int lane = threadIdx.x & 63;
  if (wave >= N) return;
  int c = lane & 15;
  int q = lane >> 4;
  const float* hr = h + (size_t)wave * H + q * 32;
  const float* wr = lw + c * H + q * 32;
  float p = 0.f;
#pragma unroll
  for (int k = 0; k < 32; k += 4) {
    float4 a = *(const float4*)(hr + k);
    float4 w = *(const float4*)(wr + k);
    p += a.x * w.x + a.y * w.y + a.z * w.z + a.w * w.w;
  }
  p += __shfl_xor(p, 16, 64);
  p += __shfl_xor(p, 32, 64);
  float z = p + lb[c];
  float mx = z;
#pragma unroll
  for (int d = 1; d < 16; d <<= 1) mx = fmaxf(mx, __shfl_xor(mx, d, 64));
  float e = expf(z - mx);
  float s = e;
#pragma unroll
  for (int d = 1; d < 16; d <<= 1) s += __shfl_xor(s, d, 64);
  if (q == 0) out[(size_t)wave * 16 + c] = z - mx - logf(s);
}

extern "C" void kernel_launch(void* const* d_in, const int* in_sizes, int n_in,
                              void* d_out, int out_size, void* d_ws, size_t ws_size,
                              hipStream_t stream) {
  const float* x   = (const float*)d_in[0];
  const int*   ei  = (const int*)d_in[1];
  const float* W   = (const float*)d_in[2];
  const float* wih = (const float*)d_in[3];
  const float* whh = (const float*)d_in[4];
  const float* bih = (const float*)d_in[5];
  const float* bhh = (const float*)d_in[6];
  const float* lw  = (const float*)d_in[7];
  const float* lb  = (const float*)d_in[8];
  float* out = (float*)d_out;

  int N = in_sizes[0] / 64;   // 50000
  int E = in_sizes[1] / 2;    // 800000
  const int* src = ei;
  const int* dst = ei + E;

  size_t NH = (size_t)N * H;
  float* hf  = (float*)d_ws;                 // [N,H] fp32 final h (layer 3 only)
  bf16* hb0  = (bf16*)(hf + NH);             // [N,H] bf16 h ping
  bf16* hb1  = hb0 + NH;                     // [N,H] bf16 h pong
  bf16* Gb   = hb1 + NH;                     // [3][3H,H]
  bf16* whhb = Gb + 3 * 3 * H * H;           // [3H,H]
  int* deg     = (int*)(whhb + 3 * H * H);
  int* rowptr  = deg + N;                    // N+1
  int* cursor  = rowptr + N + 1;             // N
  int* bsums   = cursor + N;                 // <=256
  int* csr_src = bsums + 256;                // E

  int nb_nh = (int)((NH + 255) / 256);
  int nb_e  = (E + 255) / 256;
  int nb_n  = (N + 255) / 256;

  k_init_h<<<nb_nh, 256, 0, stream>>>(x, hb0, N);
  k_cvt<<<(3 * H * H + 255) / 256, 256, 0, stream>>>(whh, whhb, 3 * H * H);
  k_G<<<(3 * 3 * H * H + 255) / 256, 256, 0, stream>>>(W, wih, Gb);

  hipMemsetAsync(deg, 0, (size_t)N * sizeof(int), stream);
  k_count<<<nb_e, 256, 0, stream>>>(dst, deg, E);
  k_bsum<<<nb_n, 256, 0, stream>>>(deg, bsums, N);
  k_bscan<<<1, 256, 0, stream>>>(bsums, nb_n);
  k_scan2<<<nb_n, 256, 0, stream>>>(deg, bsums, rowptr, cursor, N, E);
  k_fill<<<nb_e, 256, 0, stream>>>(src, dst, cursor, csr_src, E);

  int nb_layer = (N + 31) / 32;
  bf16* hbp[2] = {hb0, hb1};
  for (int l = 0; l < 3; l++) {
    bf16* hin  = hbp[l & 1];
    bf16* hout = hbp[(l + 1) & 1];
    k_layer<<<nb_layer, 512, 0, stream>>>(hin, hout, (l == 2) ? hf : nullptr,
                                          Gb + (size_t)l * 3 * H * H, whhb,
                                          bih, bhh, rowptr, csr_src, N);
  }

  k_classify<<<(N + 3) / 4, 256, 0, stream>>>(hf, lw, lb, out, N);
}